// Round 3
// baseline (104.814 us; speedup 1.0000x reference)
//
#include <hip/hip_runtime.h>
#include <hip/hip_bf16.h>
#include <stdint.h>

typedef __attribute__((ext_vector_type(8))) short bf16x8;
typedef __attribute__((ext_vector_type(4))) float f32x4;

#define NN 1024     // nodes
#define KD 512      // 2*LDIMS
#define NC 256      // 2*HID
#define H2 64       // HID2

// ws layout (bytes)
#define OFF_WT   0            // Wt bf16 [256][512]  = 262,144
#define OFF_WHB  262144       // Whb bf16 [64][256]  =  32,768
#define OFF_PT   294912       // Pt f32  [64][1024]  = 262,144
#define OFF_QT   557056       // Qt f32  [64][1024]  = 262,144

#define TANH_SCALE 2.8853900817779268f   // 2*log2(e)

static __device__ __forceinline__ ushort f2bf(float f) {
    uint32_t u = __builtin_bit_cast(uint32_t, f);
    uint32_t r = (u + 0x7fffu + ((u >> 16) & 1u)) >> 16;
    return (ushort)r;
}

// ---------------- K0': transpose+convert weights only ----------------
// Wt[c][k] bf16 (c: cat-col 0..255, k: 0..511); Whb[d][c] bf16.
__global__ __launch_bounds__(256) void k0_pack(const float* __restrict__ W_foh,
                                               const float* __restrict__ W_fom,
                                               const float* __restrict__ W_hid2,
                                               ushort* __restrict__ Wt,
                                               ushort* __restrict__ Whb) {
    int tid = blockIdx.x * 256 + threadIdx.x;
    if (tid < 131072) {
        int c = tid & 255, k = tid >> 8;
        float v = (c < 128) ? W_foh[k * 128 + c] : W_fom[k * 128 + c - 128];
        Wt[c * 512 + k] = f2bf(v);
    } else if (tid < 147456) {
        int t3 = tid - 131072;
        int d = t3 & 63, c = t3 >> 6;
        Whb[d * 256 + c] = f2bf(W_hid2[c * 64 + d]);
    }
}

// ---------------- KA: fused  h=tanh(xf@Wcat+cb)  then  P/Q = h@Whid2half ----------------
// 128 blocks: (itile 0..63) x (half 0..1). 4 waves.
// Stage 1: each wave owns 2 n-tiles of the 128-col half, full K=512,
//          A-frags converted f32->bf16 on the fly from x.
// Stage 2: h (bf16, LDS, stride-136 pad) @ Whb-half -> Pt/Qt transposed f32.
__global__ __launch_bounds__(256) void kA_fused(const float* __restrict__ x,
                                                const ushort* __restrict__ Wt,
                                                const ushort* __restrict__ Whb,
                                                const float* __restrict__ cat_bias,
                                                const float* __restrict__ hid2_bias,
                                                float* __restrict__ Pt,
                                                float* __restrict__ Qt) {
    __shared__ ushort hl[16 * 136];     // [16 rows][128 cols] pad->136 (272B stride)
    int lane = threadIdx.x & 63;
    int wave = threadIdx.x >> 6;
    int b = blockIdx.x;
    int half = b & 1;
    int itile = b >> 1;
    int i0 = itile * 16;
    int l15 = lane & 15;
    int kq = lane >> 4;                 // 0..3
    int kofs = kq * 8;

    // ---- stage 1 ----
    const float* xr = x + (i0 + l15) * 512 + kofs;
    int nt0 = wave * 2;
    const ushort* B0 = Wt + (half * 128 + nt0 * 16 + l15) * 512 + kofs;
    const ushort* B1 = B0 + 16 * 512;
    f32x4 acc0 = {0.f, 0.f, 0.f, 0.f};
    f32x4 acc1 = {0.f, 0.f, 0.f, 0.f};
#pragma unroll
    for (int s = 0; s < 16; ++s) {
        float4 xa = *(const float4*)(xr + s * 32);
        float4 xb = *(const float4*)(xr + s * 32 + 4);
        bf16x8 a;
        a[0] = (short)f2bf(xa.x); a[1] = (short)f2bf(xa.y);
        a[2] = (short)f2bf(xa.z); a[3] = (short)f2bf(xa.w);
        a[4] = (short)f2bf(xb.x); a[5] = (short)f2bf(xb.y);
        a[6] = (short)f2bf(xb.z); a[7] = (short)f2bf(xb.w);
        bf16x8 b0 = *(const bf16x8*)(B0 + s * 32);
        bf16x8 b1 = *(const bf16x8*)(B1 + s * 32);
        acc0 = __builtin_amdgcn_mfma_f32_16x16x32_bf16(a, b0, acc0, 0, 0, 0);
        acc1 = __builtin_amdgcn_mfma_f32_16x16x32_bf16(a, b1, acc1, 0, 0, 0);
    }
    // tanh epilogue -> hl
    {
        int c0 = nt0 * 16 + l15;        // local col in [0,128)
        float cb0 = cat_bias[half * 128 + c0];
        float cb1 = cat_bias[half * 128 + c0 + 16];
#pragma unroll
        for (int r = 0; r < 4; ++r) {
            int row = kq * 4 + r;
            float v0 = acc0[r] + cb0;
            float v1 = acc1[r] + cb1;
            float t0 = 1.0f - 2.0f * __builtin_amdgcn_rcpf(exp2f(v0 * TANH_SCALE) + 1.0f);
            float t1 = 1.0f - 2.0f * __builtin_amdgcn_rcpf(exp2f(v1 * TANH_SCALE) + 1.0f);
            hl[row * 136 + c0] = f2bf(t0);
            hl[row * 136 + c0 + 16] = f2bf(t1);
        }
    }
    __syncthreads();

    // ---- stage 2: [16][128] @ [128][64] ----
    int dt = wave;                      // d-tile 0..3
    const ushort* B2 = Whb + (dt * 16 + l15) * 256 + half * 128 + kofs;
    f32x4 acc = {0.f, 0.f, 0.f, 0.f};
#pragma unroll
    for (int s = 0; s < 4; ++s) {
        bf16x8 a = *(const bf16x8*)(&hl[l15 * 136 + kofs + s * 32]);
        bf16x8 bb = *(const bf16x8*)(B2 + s * 32);
        acc = __builtin_amdgcn_mfma_f32_16x16x32_bf16(a, bb, acc, 0, 0, 0);
    }
    int d = dt * 16 + l15;
    float* out = half ? Qt : Pt;
    float badd = half ? 0.0f : hid2_bias[d];
#pragma unroll
    for (int r = 0; r < 4; ++r) {
        int i = i0 + kq * 4 + r;
        out[d * 1024 + i] = (acc[r] + badd) * TANH_SCALE;
    }
}

// ---------------- K3: scores[i][j] = base + sum_d w'_d / (exp2(P+Q)+1) ----------------
// 512 blocks: 16 i-tiles x 32 j-tiles of 64x32. 256 thr, 4(i)x2(j) per thread.
__global__ __launch_bounds__(256) void k3_scores(const float* __restrict__ Pt,
                                                 const float* __restrict__ Qt,
                                                 const float* __restrict__ W_out,
                                                 const float* __restrict__ out_bias,
                                                 float* __restrict__ out) {
    __shared__ float Pl[64][68];
    __shared__ float Ql[64][36];
    __shared__ float wl[64];
    int t = threadIdx.x;
    int b = blockIdx.x;
    int i0 = (b >> 5) * 64;
    int j0 = (b & 31) * 32;
    {   // P tile: 64 d-rows x 64 i-cols
        int rowd = t >> 2;
        int cch = (t & 3) * 16;
        const float4* ps = (const float4*)(Pt + rowd * 1024 + i0 + cch);
#pragma unroll
        for (int u = 0; u < 4; ++u) *(float4*)(&Pl[rowd][cch + u * 4]) = ps[u];
    }
    {   // Q tile: 64 d-rows x 32 j-cols
        int rowd = t >> 2;
        int cch = (t & 3) * 8;
        const float4* qs = (const float4*)(Qt + rowd * 1024 + j0 + cch);
        *(float4*)(&Ql[rowd][cch]) = qs[0];
        *(float4*)(&Ql[rowd][cch + 4]) = qs[1];
    }
    if (t < 64) wl[t] = -2.0f * W_out[t];
    float base = out_bias[0];
#pragma unroll
    for (int d = 0; d < 64; ++d) base += W_out[d];   // uniform s_loads
    __syncthreads();

    int il = (t & 15) * 4;
    int jl = (t >> 4) * 2;
    float acc[4][2] = {};
#pragma unroll 8
    for (int d = 0; d < 64; ++d) {
        f32x4 p = *(const f32x4*)(&Pl[d][il]);
        float q0 = Ql[d][jl], q1 = Ql[d][jl + 1];
        float w = wl[d];
#pragma unroll
        for (int a = 0; a < 4; ++a) {
            float e0 = exp2f(p[a] + q0);
            float r0 = __builtin_amdgcn_rcpf(e0 + 1.0f);
            acc[a][0] = fmaf(w, r0, acc[a][0]);
            float e1 = exp2f(p[a] + q1);
            float r1 = __builtin_amdgcn_rcpf(e1 + 1.0f);
            acc[a][1] = fmaf(w, r1, acc[a][1]);
        }
    }
#pragma unroll
    for (int a = 0; a < 4; ++a) {
        float2 v;
        v.x = base + acc[a][0];
        v.y = base + acc[a][1];
        *(float2*)(&out[(i0 + il + a) * 1024 + j0 + jl]) = v;
    }
}

extern "C" void kernel_launch(void* const* d_in, const int* in_sizes, int n_in,
                              void* d_out, int out_size, void* d_ws, size_t ws_size,
                              hipStream_t stream) {
    const float* x        = (const float*)d_in[0];
    const float* W_foh    = (const float*)d_in[1];
    const float* W_fom    = (const float*)d_in[2];
    const float* cat_bias = (const float*)d_in[3];
    const float* W_hid2   = (const float*)d_in[4];
    const float* hid2_bias= (const float*)d_in[5];
    const float* W_out    = (const float*)d_in[6];
    const float* out_bias = (const float*)d_in[7];

    char* ws = (char*)d_ws;
    ushort* Wt  = (ushort*)(ws + OFF_WT);
    ushort* Whb = (ushort*)(ws + OFF_WHB);
    float*  Pt  = (float*)(ws + OFF_PT);
    float*  Qt  = (float*)(ws + OFF_QT);

    k0_pack<<<576, 256, 0, stream>>>(W_foh, W_fom, W_hid2, Wt, Whb);
    kA_fused<<<128, 256, 0, stream>>>(x, Wt, Whb, cat_bias, hid2_bias, Pt, Qt);
    k3_scores<<<512, 256, 0, stream>>>(Pt, Qt, W_out, out_bias, (float*)d_out);
}